// Round 6
// baseline (226.250 us; speedup 1.0000x reference)
//
#include <hip/hip_runtime.h>
#include <hip/hip_bf16.h>

// ---------------------------------------------------------------------------
// ASGNN round 6: fuse gather_mean + gemm_mfma (aggb round-trip eliminated),
// pack ebuf to u32, fewer launches.
//  K0 cvt_prep   : xb = bf16(x) ; Wb[j][k] = bf16([W1l|W1r]) (j-major)
//  K1 hist_k     : hist[g][b] = #edges of chunk g with dst in bucket b
//  K2 sumscan_k  : bbase = exscan_b(sum_g hist[g][b])
//  K3 colscan_k  : gbase[b][g] = bbase[b] + prefix_g
//  K4 scatter2_k : ebuf[cur++] = (local_dst<<17)|src   (LDS cursors)
//  K5 fill3_k    : per-bucket counts -> row_ptr ; csr[lcur[dst]++] = src
//  K6 fused_gg   : per 128-row block: gather-mean into LDS, then MFMA GEMM
//                  h = relu([agg|x] @ Wb^T + b1l); t=W2l.h, r=W2r.h (atomics)
//  K7 final_k    : z = mean_s t[s] + b2l + r ; out = mu + eps*exp(logvar)
// ---------------------------------------------------------------------------

#define F_DIM 128
#define NFEAT2 256
#define BUK_BITS 7
#define BUK_SZ 128
#define GROUPS 128

typedef __bf16 b8 __attribute__((ext_vector_type(8)));
typedef float  f4 __attribute__((ext_vector_type(4)));

__device__ inline float bf2f(unsigned short u) {
    unsigned int v = ((unsigned int)u) << 16;
    return __uint_as_float(v);
}
__device__ inline unsigned short f2bf(float f) {
    unsigned int u = __float_as_uint(f);
    u += 0x7fffu + ((u >> 16) & 1u);
    return (unsigned short)(u >> 16);
}
__device__ inline void acc8(float* a, uint4 r) {
    a[0] += bf2f(r.x & 0xffff); a[1] += bf2f(r.x >> 16);
    a[2] += bf2f(r.y & 0xffff); a[3] += bf2f(r.y >> 16);
    a[4] += bf2f(r.z & 0xffff); a[5] += bf2f(r.z >> 16);
    a[6] += bf2f(r.w & 0xffff); a[7] += bf2f(r.w >> 16);
}

// merged: blocks [0,256) do prep_w, blocks [256, 256+n4/256) do cvt_x
__global__ void cvt_prep(const float* __restrict__ x, unsigned short* __restrict__ xb,
                         const float* __restrict__ W1l, const float* __restrict__ W1r,
                         unsigned short* __restrict__ Wb, int n4) {
    int b = blockIdx.x;
    if (b < 256) {
        int idx = b * 256 + threadIdx.x;
        int j = idx >> 8, k = idx & 255;
        float v = (k < F_DIM) ? W1l[j * F_DIM + k] : W1r[j * F_DIM + (k - F_DIM)];
        Wb[j * NFEAT2 + k] = f2bf(v);
    } else {
        int i = (b - 256) * 256 + threadIdx.x;
        if (i >= n4) return;
        float4 v = *(const float4*)(x + (size_t)i * 4);
        ushort4 o;
        o.x = f2bf(v.x); o.y = f2bf(v.y); o.z = f2bf(v.z); o.w = f2bf(v.w);
        *(ushort4*)(xb + (size_t)i * 4) = o;
    }
}

__global__ __launch_bounds__(256)
void hist_k(const int* __restrict__ dst, int* __restrict__ hist,
            int E, int nbuk, int chunk) {
    __shared__ int h[1024];
    int g = blockIdx.x, tid = threadIdx.x;
    for (int i = tid; i < nbuk; i += 256) h[i] = 0;
    __syncthreads();
    int e0 = g * chunk, e1 = min(e0 + chunk, E);
    for (int e = e0 + tid; e < e1; e += 256)
        atomicAdd(&h[dst[e] >> BUK_BITS], 1);
    __syncthreads();
    for (int i = tid; i < nbuk; i += 256) hist[g * nbuk + i] = h[i];
}

// fused column-sum over groups + single-block exclusive scan -> bbase
__global__ __launch_bounds__(1024)
void sumscan_k(const int* __restrict__ hist, int* __restrict__ bbase, int nbuk) {
    __shared__ int wsum[16];
    int tid = threadIdx.x, lane = tid & 63, w = tid >> 6;
    int v = 0;
    if (tid < nbuk)
        for (int g = 0; g < GROUPS; ++g) v += hist[g * nbuk + tid];
    int sc = v;
    #pragma unroll
    for (int off = 1; off < 64; off <<= 1) {
        int t = __shfl_up(sc, off, 64);
        if (lane >= off) sc += t;
    }
    if (lane == 63) wsum[w] = sc;
    __syncthreads();
    int woff = 0;
    for (int k = 0; k < w; ++k) woff += wsum[k];
    if (tid < nbuk) bbase[tid] = sc - v + woff;
    if (tid == 1023) bbase[nbuk] = woff + sc;
}

__global__ __launch_bounds__(GROUPS)
void colscan_k(const int* __restrict__ hist, const int* __restrict__ bbase,
               int* __restrict__ gbase, int nbuk) {
    __shared__ int ws2[2];
    int b = blockIdx.x, tid = threadIdx.x;
    int lane = tid & 63, w = tid >> 6;
    int v = hist[tid * nbuk + b];
    int sc = v;
    #pragma unroll
    for (int off = 1; off < 64; off <<= 1) {
        int t = __shfl_up(sc, off, 64);
        if (lane >= off) sc += t;
    }
    if (lane == 63) ws2[w] = sc;
    __syncthreads();
    int excl = sc - v + (w ? ws2[0] : 0);
    gbase[b * GROUPS + tid] = bbase[b] + excl;
}

// packed placement: ebuf entry = (local_dst << 17) | src   (src < 2^17)
__global__ __launch_bounds__(256)
void scatter2_k(const int* __restrict__ src, const int* __restrict__ dst,
                const int* __restrict__ gbase, unsigned* __restrict__ ebuf,
                int E, int nbuk, int chunk) {
    __shared__ int lcur[1024];
    int g = blockIdx.x, tid = threadIdx.x;
    for (int i = tid; i < nbuk; i += 256) lcur[i] = gbase[i * GROUPS + g];
    __syncthreads();
    int e0 = g * chunk, e1 = min(e0 + chunk, E);
    for (int e = e0 + tid; e < e1; e += 256) {
        int s = src[e], d = dst[e];
        int p = atomicAdd(&lcur[d >> BUK_BITS], 1);
        ebuf[p] = ((unsigned)(d & (BUK_SZ - 1)) << 17) | (unsigned)s;
    }
}

__global__ __launch_bounds__(256)
void fill3_k(const unsigned* __restrict__ ebuf, const int* __restrict__ bbase,
             int* __restrict__ row_ptr, int* __restrict__ csr, int Nn, int nbuk) {
    __shared__ int ncnt[BUK_SZ];
    __shared__ int lcur[BUK_SZ];
    __shared__ int ws2[2];
    int b = blockIdx.x, tid = threadIdx.x;
    int node0 = b << BUK_BITS;
    int base = bbase[b], endp = bbase[b + 1];
    if (tid < BUK_SZ) ncnt[tid] = 0;
    __syncthreads();
    for (int i = base + tid; i < endp; i += 256)
        atomicAdd(&ncnt[ebuf[i] >> 17], 1);
    __syncthreads();
    int v = 0, sc = 0;
    int lane = tid & 63, w = tid >> 6;
    if (tid < BUK_SZ) {
        v = ncnt[tid];
        sc = v;
        #pragma unroll
        for (int off = 1; off < 64; off <<= 1) {
            int t = __shfl_up(sc, off, 64);
            if (lane >= off) sc += t;
        }
        if (lane == 63) ws2[w] = sc;
    }
    __syncthreads();
    if (tid < BUK_SZ) {
        int pos = base + sc - v + (w ? ws2[0] : 0);
        lcur[tid] = pos;
        if (node0 + tid < Nn) row_ptr[node0 + tid] = pos;
    }
    if (b == nbuk - 1 && tid == 0) row_ptr[Nn] = endp;
    __syncthreads();
    for (int i = base + tid; i < endp; i += 256) {
        unsigned e = ebuf[i];
        int p = atomicAdd(&lcur[e >> 17], 1);
        csr[p] = (int)(e & 0x1FFFFu);
    }
}

// -------- fused gather-mean + MFMA GEMM --------
// 512 thr / 8 waves per 128-row tile. LDS: AggL 32K + AxL 16K + BL 32K = 80K
// -> 2 blocks/CU. Wave grid 2x4: each wave 64 rows x 64 cols of the 128x256
// output. All LDS XOR-swizzled: byte ^= (row&7)<<4.
__global__ __launch_bounds__(512, 4)
void fused_gg(const unsigned short* __restrict__ xb, const int* __restrict__ row_ptr,
              const int* __restrict__ csr, const unsigned short* __restrict__ Wb,
              const float* __restrict__ b1l, const float* __restrict__ W2l,
              const float* __restrict__ W2r, float* __restrict__ tv,
              float* __restrict__ rv, int Nn) {
    __shared__ unsigned short AggL[128 * 128];  // rowstride 256 B
    __shared__ unsigned short AxL[128 * 64];    // rowstride 128 B
    __shared__ unsigned short BL[256 * 64];     // rowstride 128 B
    int tid = threadIdx.x;
    int m0 = blockIdx.x * 128;

    // ---- phase 1: gather-mean of x[nbr] into AggL (bf16) ----
    #pragma unroll
    for (int pass = 0; pass < 4; ++pass) {
        int ml = pass * 32 + (tid >> 4);
        int q = tid & 15;
        int gn = m0 + ml;
        float a[8] = {};
        int beg = 0, end = 0;
        if (gn < Nn) { beg = row_ptr[gn]; end = row_ptr[gn + 1]; }
        int j = beg;
        for (; j + 1 < end; j += 2) {
            int s0 = csr[j], s1 = csr[j + 1];
            uint4 r0 = *(const uint4*)(xb + (size_t)s0 * F_DIM + q * 8);
            uint4 r1 = *(const uint4*)(xb + (size_t)s1 * F_DIM + q * 8);
            acc8(a, r0);
            acc8(a, r1);
        }
        if (j < end) {
            uint4 r0 = *(const uint4*)(xb + (size_t)csr[j] * F_DIM + q * 8);
            acc8(a, r0);
        }
        float inv = (end > beg) ? 1.0f / (float)(end - beg) : 0.0f;
        uint4 o;
        o.x = (unsigned)f2bf(a[0] * inv) | ((unsigned)f2bf(a[1] * inv) << 16);
        o.y = (unsigned)f2bf(a[2] * inv) | ((unsigned)f2bf(a[3] * inv) << 16);
        o.z = (unsigned)f2bf(a[4] * inv) | ((unsigned)f2bf(a[5] * inv) << 16);
        o.w = (unsigned)f2bf(a[6] * inv) | ((unsigned)f2bf(a[7] * inv) << 16);
        int byte = (ml * 256 + q * 16) ^ ((ml & 7) << 4);
        *(uint4*)((char*)AggL + byte) = o;
    }
    __syncthreads();

    // ---- phase 2: MFMA K-loop ----
    int lane = tid & 63, wid = tid >> 6;
    int wm = wid >> 2, wj = wid & 3;
    f4 acc[4][4] = {};

    for (int kstep = 0; kstep < 4; ++kstep) {
        if (kstep >= 2) {
            int kb = (kstep & 1) * 64;   // x feats 0..63 / 64..127
            #pragma unroll
            for (int p = 0; p < 2; ++p) {
                int c = tid + p * 512;
                int m = c >> 3, kc = c & 7;
                int gn = m0 + m;
                uint4 v = make_uint4(0u, 0u, 0u, 0u);
                if (gn < Nn) v = *(const uint4*)(xb + (size_t)gn * F_DIM + kb + kc * 8);
                int byte = (m * 128 + kc * 16) ^ ((m & 7) << 4);
                *(uint4*)((char*)AxL + byte) = v;
            }
        }
        #pragma unroll
        for (int p = 0; p < 4; ++p) {
            int c = tid + p * 512;
            int jj = c >> 3, kc = c & 7;
            uint4 v = *(const uint4*)(Wb + (size_t)jj * NFEAT2 + kstep * 64 + kc * 8);
            int byte = (jj * 128 + kc * 16) ^ ((jj & 7) << 4);
            *(uint4*)((char*)BL + byte) = v;
        }
        __syncthreads();

        #pragma unroll
        for (int ks = 0; ks < 2; ++ks) {
            b8 af[4], bfr[4];
            #pragma unroll
            for (int fm = 0; fm < 4; ++fm) {
                int m = (wm << 6) + (fm << 4) + (lane & 15);
                if (kstep < 2) {
                    int k = kstep * 64 + ks * 32 + ((lane >> 4) << 3);
                    int byte = (m * 256 + k * 2) ^ ((m & 7) << 4);
                    af[fm] = *(const b8*)((const char*)AggL + byte);
                } else {
                    int kk = ks * 32 + ((lane >> 4) << 3);
                    int byte = (m * 128 + kk * 2) ^ ((m & 7) << 4);
                    af[fm] = *(const b8*)((const char*)AxL + byte);
                }
            }
            #pragma unroll
            for (int fj = 0; fj < 4; ++fj) {
                int jj = (wj << 6) + (fj << 4) + (lane & 15);
                int kk = ks * 32 + ((lane >> 4) << 3);
                int byte = (jj * 128 + kk * 2) ^ ((jj & 7) << 4);
                bfr[fj] = *(const b8*)((const char*)BL + byte);
            }
            #pragma unroll
            for (int fm = 0; fm < 4; ++fm)
                #pragma unroll
                for (int fj = 0; fj < 4; ++fj)
                    acc[fm][fj] = __builtin_amdgcn_mfma_f32_16x16x32_bf16(
                        af[fm], bfr[fj], acc[fm][fj], 0, 0, 0);
        }
        __syncthreads();
    }

    // ---- epilogue: h = relu(acc + b1l); t += W2l.h ; r += W2r.h ----
    float bb[4], wl[4], wr[4];
    #pragma unroll
    for (int fj = 0; fj < 4; ++fj) {
        int j_abs = (wj << 6) + (fj << 4) + (lane & 15);
        bb[fj] = b1l[j_abs];
        wl[fj] = W2l[j_abs];
        wr[fj] = W2r[j_abs];
    }
    #pragma unroll
    for (int fm = 0; fm < 4; ++fm) {
        #pragma unroll
        for (int reg = 0; reg < 4; ++reg) {
            int row = m0 + (wm << 6) + (fm << 4) + ((lane >> 4) << 2) + reg;
            float tp = 0.f, rp = 0.f;
            #pragma unroll
            for (int fj = 0; fj < 4; ++fj) {
                float h = fmaxf(acc[fm][fj][reg] + bb[fj], 0.0f);
                tp += wl[fj] * h;
                rp += wr[fj] * h;
            }
            #pragma unroll
            for (int mask = 1; mask < 16; mask <<= 1) {
                tp += __shfl_xor(tp, mask, 64);
                rp += __shfl_xor(rp, mask, 64);
            }
            if ((lane & 15) == 0 && row < Nn) {
                atomicAdd(&tv[row], tp);
                atomicAdd(&rv[row], rp);
            }
        }
    }
}

__global__ void final_k(const float* __restrict__ t, const int* __restrict__ row_ptr,
                        const int* __restrict__ csr, const float* __restrict__ r,
                        const float* __restrict__ b2l,
                        const float* __restrict__ Wmu, const float* __restrict__ bmu,
                        const float* __restrict__ Wlv, const float* __restrict__ blv,
                        const float* __restrict__ eps, float* __restrict__ out, int Nn) {
    int i = blockIdx.x * blockDim.x + threadIdx.x;
    if (i >= Nn) return;
    int beg = row_ptr[i], end = row_ptr[i + 1];
    float s = 0.f;
    for (int j = beg; j < end; ++j) s += t[csr[j]];
    float z = s / fmaxf((float)(end - beg), 1.0f) + b2l[0] + r[i];
    float mu = z * Wmu[0] + bmu[0];
    float lv = z * Wlv[0] + blv[0];
    out[i] = mu + eps[i] * expf(lv);
}

extern "C" void kernel_launch(void* const* d_in, const int* in_sizes, int n_in,
                              void* d_out, int out_size, void* d_ws, size_t ws_size,
                              hipStream_t stream) {
    const float* x   = (const float*)d_in[0];
    const int*   ei  = (const int*)d_in[1];
    const float* W1l = (const float*)d_in[2];
    const float* b1l = (const float*)d_in[3];
    const float* W1r = (const float*)d_in[4];
    const float* W2l = (const float*)d_in[5];
    const float* b2l = (const float*)d_in[6];
    const float* W2r = (const float*)d_in[7];
    // d_in[8..10] = Wal, bal, War : dead (softmax over size-1 axis == 1)
    const float* Wmu = (const float*)d_in[11];
    const float* bmu = (const float*)d_in[12];
    const float* Wlv = (const float*)d_in[13];
    const float* blv = (const float*)d_in[14];
    const float* eps = (const float*)d_in[15];
    float* out = (float*)d_out;

    const int Nn = in_sizes[0] / F_DIM;   // 100000
    const int E  = in_sizes[1] / 2;       // 1600000
    const int* src = ei;
    const int* dst = ei + E;
    const int nbuk = (Nn + BUK_SZ - 1) >> BUK_BITS;      // 782
    const int chunk = (E + GROUPS - 1) / GROUPS;         // 12500

    char* ws = (char*)d_ws;
    float*          tv      = (float*)(ws + 0);               // N
    float*          rv      = (float*)(ws + 400000);          // N
    int*            row_ptr = (int*)(ws + 800000);            // N+1
    int*            bbase   = (int*)(ws + 1200064);           // nbuk+1
    int*            hist    = (int*)(ws + 1203264);           // GROUPS*nbuk
    int*            gbase   = (int*)(ws + 1603648);           // nbuk*GROUPS
    int*            csr     = (int*)(ws + 2004032);           // E ints
    unsigned*       ebuf    = (unsigned*)(ws + 8404032);      // E u32 (packed)
    unsigned short* xb      = (unsigned short*)(ws + 14804032);  // N*128 bf16
    unsigned short* Wb      = (unsigned short*)(ws + 40404032);  // 256*256 bf16

    hipMemsetAsync(ws, 0, 800000, stream);   // tv, rv

    int n4 = Nn * F_DIM / 4;
    cvt_prep<<<256 + (n4 + 255) / 256, 256, 0, stream>>>(x, xb, W1l, W1r, Wb, n4);

    hist_k<<<GROUPS, 256, 0, stream>>>(dst, hist, E, nbuk, chunk);
    sumscan_k<<<1, 1024, 0, stream>>>(hist, bbase, nbuk);
    colscan_k<<<nbuk, GROUPS, 0, stream>>>(hist, bbase, gbase, nbuk);
    scatter2_k<<<GROUPS, 256, 0, stream>>>(src, dst, gbase, ebuf, E, nbuk, chunk);
    fill3_k<<<nbuk, 256, 0, stream>>>(ebuf, bbase, row_ptr, csr, Nn, nbuk);

    fused_gg<<<(Nn + 127) / 128, 512, 0, stream>>>(xb, row_ptr, csr, Wb, b1l,
                                                   W2l, W2r, tv, rv, Nn);

    final_k<<<(Nn + 255) / 256, 256, 0, stream>>>(tv, row_ptr, csr, rv, b2l,
                                                  Wmu, bmu, Wlv, blv, eps, out, Nn);
}

// Round 7
// 209.417 us; speedup vs baseline: 1.0804x; 1.0804x over previous
//
#include <hip/hip_runtime.h>
#include <hip/hip_bf16.h>

// ---------------------------------------------------------------------------
// ASGNN round 7: un-fuse (round-6 fusion lost occupancy); keep u32 ebuf +
// merged prep. ILP-unrolled gather; single-pass-A GEMM (BJ=256) with
// LDS-reduced epilogue (no atomics, no memset).
//  K0 cvt_prep   : xb = bf16(x) ; Wb[j][k] = bf16([W1l|W1r]) (j-major)
//  K1 hist_k     : hist[g][b] = #edges of chunk g with dst in bucket b
//  K2 sumscan_k  : bbase = exscan_b(sum_g hist[g][b])
//  K3 colscan_k  : gbase[b][g] = bbase[b] + prefix_g
//  K4 scatter2_k : ebuf[cur++] = (local_dst<<17)|src   (LDS cursors)
//  K5 fill3_k    : per-bucket counts -> row_ptr ; csr[lcur[dst]++] = src
//  K6 gather_mean: aggb[n] = bf16(mean_{s in nbr(n)} xb[s])  (4-way ILP)
//  K7 gemm_big   : h = relu([aggb|xb] @ Wb^T + b1l); t=W2l.h, r=W2r.h
//                  (128x256 per block, LDS-reduced t/r, plain stores)
//  K8 final_k    : z = mean_s t[s] + b2l + r ; out = mu + eps*exp(logvar)
// ---------------------------------------------------------------------------

#define F_DIM 128
#define NFEAT2 256
#define BUK_BITS 7
#define BUK_SZ 128
#define GROUPS 128

typedef __bf16 b8 __attribute__((ext_vector_type(8)));
typedef float  f4 __attribute__((ext_vector_type(4)));

__device__ inline float bf2f(unsigned short u) {
    unsigned int v = ((unsigned int)u) << 16;
    return __uint_as_float(v);
}
__device__ inline unsigned short f2bf(float f) {
    unsigned int u = __float_as_uint(f);
    u += 0x7fffu + ((u >> 16) & 1u);
    return (unsigned short)(u >> 16);
}
__device__ inline void acc4(float* a, uint2 r) {
    a[0] += bf2f(r.x & 0xffff); a[1] += bf2f(r.x >> 16);
    a[2] += bf2f(r.y & 0xffff); a[3] += bf2f(r.y >> 16);
}

__global__ void cvt_prep(const float* __restrict__ x, unsigned short* __restrict__ xb,
                         const float* __restrict__ W1l, const float* __restrict__ W1r,
                         unsigned short* __restrict__ Wb, int n4) {
    int b = blockIdx.x;
    if (b < 256) {
        int idx = b * 256 + threadIdx.x;
        int j = idx >> 8, k = idx & 255;
        float v = (k < F_DIM) ? W1l[j * F_DIM + k] : W1r[j * F_DIM + (k - F_DIM)];
        Wb[j * NFEAT2 + k] = f2bf(v);
    } else {
        int i = (b - 256) * 256 + threadIdx.x;
        if (i >= n4) return;
        float4 v = *(const float4*)(x + (size_t)i * 4);
        ushort4 o;
        o.x = f2bf(v.x); o.y = f2bf(v.y); o.z = f2bf(v.z); o.w = f2bf(v.w);
        *(ushort4*)(xb + (size_t)i * 4) = o;
    }
}

__global__ __launch_bounds__(256)
void hist_k(const int* __restrict__ dst, int* __restrict__ hist,
            int E, int nbuk, int chunk) {
    __shared__ int h[1024];
    int g = blockIdx.x, tid = threadIdx.x;
    for (int i = tid; i < nbuk; i += 256) h[i] = 0;
    __syncthreads();
    int e0 = g * chunk, e1 = min(e0 + chunk, E);
    for (int e = e0 + tid; e < e1; e += 256)
        atomicAdd(&h[dst[e] >> BUK_BITS], 1);
    __syncthreads();
    for (int i = tid; i < nbuk; i += 256) hist[g * nbuk + i] = h[i];
}

__global__ __launch_bounds__(1024)
void sumscan_k(const int* __restrict__ hist, int* __restrict__ bbase, int nbuk) {
    __shared__ int wsum[16];
    int tid = threadIdx.x, lane = tid & 63, w = tid >> 6;
    int v = 0;
    if (tid < nbuk)
        for (int g = 0; g < GROUPS; ++g) v += hist[g * nbuk + tid];
    int sc = v;
    #pragma unroll
    for (int off = 1; off < 64; off <<= 1) {
        int t = __shfl_up(sc, off, 64);
        if (lane >= off) sc += t;
    }
    if (lane == 63) wsum[w] = sc;
    __syncthreads();
    int woff = 0;
    for (int k = 0; k < w; ++k) woff += wsum[k];
    if (tid < nbuk) bbase[tid] = sc - v + woff;
    if (tid == 1023) bbase[nbuk] = woff + sc;
}

__global__ __launch_bounds__(GROUPS)
void colscan_k(const int* __restrict__ hist, const int* __restrict__ bbase,
               int* __restrict__ gbase, int nbuk) {
    __shared__ int ws2[2];
    int b = blockIdx.x, tid = threadIdx.x;
    int lane = tid & 63, w = tid >> 6;
    int v = hist[tid * nbuk + b];
    int sc = v;
    #pragma unroll
    for (int off = 1; off < 64; off <<= 1) {
        int t = __shfl_up(sc, off, 64);
        if (lane >= off) sc += t;
    }
    if (lane == 63) ws2[w] = sc;
    __syncthreads();
    int excl = sc - v + (w ? ws2[0] : 0);
    gbase[b * GROUPS + tid] = bbase[b] + excl;
}

__global__ __launch_bounds__(256)
void scatter2_k(const int* __restrict__ src, const int* __restrict__ dst,
                const int* __restrict__ gbase, unsigned* __restrict__ ebuf,
                int E, int nbuk, int chunk) {
    __shared__ int lcur[1024];
    int g = blockIdx.x, tid = threadIdx.x;
    for (int i = tid; i < nbuk; i += 256) lcur[i] = gbase[i * GROUPS + g];
    __syncthreads();
    int e0 = g * chunk, e1 = min(e0 + chunk, E);
    for (int e = e0 + tid; e < e1; e += 256) {
        int s = src[e], d = dst[e];
        int p = atomicAdd(&lcur[d >> BUK_BITS], 1);
        ebuf[p] = ((unsigned)(d & (BUK_SZ - 1)) << 17) | (unsigned)s;
    }
}

__global__ __launch_bounds__(256)
void fill3_k(const unsigned* __restrict__ ebuf, const int* __restrict__ bbase,
             int* __restrict__ row_ptr, int* __restrict__ csr, int Nn, int nbuk) {
    __shared__ int ncnt[BUK_SZ];
    __shared__ int lcur[BUK_SZ];
    __shared__ int ws2[2];
    int b = blockIdx.x, tid = threadIdx.x;
    int node0 = b << BUK_BITS;
    int base = bbase[b], endp = bbase[b + 1];
    if (tid < BUK_SZ) ncnt[tid] = 0;
    __syncthreads();
    for (int i = base + tid; i < endp; i += 256)
        atomicAdd(&ncnt[ebuf[i] >> 17], 1);
    __syncthreads();
    int v = 0, sc = 0;
    int lane = tid & 63, w = tid >> 6;
    if (tid < BUK_SZ) {
        v = ncnt[tid];
        sc = v;
        #pragma unroll
        for (int off = 1; off < 64; off <<= 1) {
            int t = __shfl_up(sc, off, 64);
            if (lane >= off) sc += t;
        }
        if (lane == 63) ws2[w] = sc;
    }
    __syncthreads();
    if (tid < BUK_SZ) {
        int pos = base + sc - v + (w ? ws2[0] : 0);
        lcur[tid] = pos;
        if (node0 + tid < Nn) row_ptr[node0 + tid] = pos;
    }
    if (b == nbuk - 1 && tid == 0) row_ptr[Nn] = endp;
    __syncthreads();
    for (int i = base + tid; i < endp; i += 256) {
        unsigned e = ebuf[i];
        int p = atomicAdd(&lcur[e >> 17], 1);
        csr[p] = (int)(e & 0x1FFFFu);
    }
}

// 8 nodes per block; 32 lanes/node (uint2 = 4 bf16 each); 4-edge ILP unroll
__global__ __launch_bounds__(256)
void gather_mean(const unsigned short* __restrict__ xb, const int* __restrict__ row_ptr,
                 const int* __restrict__ csr, unsigned short* __restrict__ aggb, int Nn) {
    int node = blockIdx.x * 8 + (threadIdx.x >> 5);
    int q = threadIdx.x & 31;
    if (node >= Nn) return;
    int beg = row_ptr[node], end = row_ptr[node + 1];
    float a0[4] = {}, a1[4] = {}, a2[4] = {}, a3[4] = {};
    int j = beg;
    for (; j + 3 < end; j += 4) {
        int s0 = csr[j], s1 = csr[j + 1], s2 = csr[j + 2], s3 = csr[j + 3];
        uint2 r0 = *(const uint2*)(xb + (size_t)s0 * F_DIM + q * 4);
        uint2 r1 = *(const uint2*)(xb + (size_t)s1 * F_DIM + q * 4);
        uint2 r2 = *(const uint2*)(xb + (size_t)s2 * F_DIM + q * 4);
        uint2 r3 = *(const uint2*)(xb + (size_t)s3 * F_DIM + q * 4);
        acc4(a0, r0); acc4(a1, r1); acc4(a2, r2); acc4(a3, r3);
    }
    for (; j < end; ++j) {
        uint2 r0 = *(const uint2*)(xb + (size_t)csr[j] * F_DIM + q * 4);
        acc4(a0, r0);
    }
    float inv = (end > beg) ? 1.0f / (float)(end - beg) : 0.0f;
    float s0 = (a0[0] + a1[0] + a2[0] + a3[0]) * inv;
    float s1 = (a0[1] + a1[1] + a2[1] + a3[1]) * inv;
    float s2 = (a0[2] + a1[2] + a2[2] + a3[2]) * inv;
    float s3 = (a0[3] + a1[3] + a2[3] + a3[3]) * inv;
    uint2 o;
    o.x = (unsigned)f2bf(s0) | ((unsigned)f2bf(s1) << 16);
    o.y = (unsigned)f2bf(s2) | ((unsigned)f2bf(s3) << 16);
    *(uint2*)(aggb + (size_t)node * F_DIM + q * 4) = o;
}

// 128x256 output per 512-thread block (8 waves = 2 wm x 4 wj, each 64x64).
// A read ONCE (aggb for k<128, xb for k>=128), staged 128x64 per kstep.
// LDS: AxL 16K + BL 32K + Tp/Rp 4K = 52K -> 3 blocks/CU. XOR swizzle (T2).
__global__ __launch_bounds__(512)
void gemm_big(const unsigned short* __restrict__ aggb, const unsigned short* __restrict__ xb,
              const unsigned short* __restrict__ Wb, const float* __restrict__ b1l,
              const float* __restrict__ W2l, const float* __restrict__ W2r,
              float* __restrict__ tv, float* __restrict__ rv, int Nn) {
    __shared__ unsigned short AxL[128 * 64];   // 16 KB, rowstride 128 B
    __shared__ unsigned short BL[256 * 64];    // 32 KB, rowstride 128 B
    __shared__ float TpL[128][4];
    __shared__ float RpL[128][4];
    int tid = threadIdx.x;
    int m0 = blockIdx.x * 128;
    int lane = tid & 63, wid = tid >> 6;
    int wm = wid >> 2, wj = wid & 3;

    f4 acc[4][4] = {};

    for (int kstep = 0; kstep < 4; ++kstep) {
        const unsigned short* Asrc = (kstep < 2) ? aggb : xb;
        int kb = (kstep & 1) * 64;
        #pragma unroll
        for (int p = 0; p < 2; ++p) {
            int c = tid + p * 512;
            int m = c >> 3, kc = c & 7;
            int gn = m0 + m;
            uint4 v = make_uint4(0u, 0u, 0u, 0u);
            if (gn < Nn) v = *(const uint4*)(Asrc + (size_t)gn * F_DIM + kb + kc * 8);
            int byte = (m * 128 + kc * 16) ^ ((m & 7) << 4);
            *(uint4*)((char*)AxL + byte) = v;
        }
        #pragma unroll
        for (int p = 0; p < 4; ++p) {
            int c = tid + p * 512;
            int jj = c >> 3, kc = c & 7;
            uint4 v = *(const uint4*)(Wb + (size_t)jj * NFEAT2 + kstep * 64 + kc * 8);
            int byte = (jj * 128 + kc * 16) ^ ((jj & 7) << 4);
            *(uint4*)((char*)BL + byte) = v;
        }
        __syncthreads();

        #pragma unroll
        for (int ks = 0; ks < 2; ++ks) {
            int kk = ks * 32 + ((lane >> 4) << 3);
            b8 af[4], bfr[4];
            #pragma unroll
            for (int fm = 0; fm < 4; ++fm) {
                int m = (wm << 6) + (fm << 4) + (lane & 15);
                int byte = (m * 128 + kk * 2) ^ ((m & 7) << 4);
                af[fm] = *(const b8*)((const char*)AxL + byte);
            }
            #pragma unroll
            for (int fj = 0; fj < 4; ++fj) {
                int jj = (wj << 6) + (fj << 4) + (lane & 15);
                int byte = (jj * 128 + kk * 2) ^ ((jj & 7) << 4);
                bfr[fj] = *(const b8*)((const char*)BL + byte);
            }
            #pragma unroll
            for (int fm = 0; fm < 4; ++fm)
                #pragma unroll
                for (int fj = 0; fj < 4; ++fj)
                    acc[fm][fj] = __builtin_amdgcn_mfma_f32_16x16x32_bf16(
                        af[fm], bfr[fj], acc[fm][fj], 0, 0, 0);
        }
        __syncthreads();
    }

    // epilogue: per-wave partial t/r per row -> LDS -> plain store
    float bb[4], wl[4], wr[4];
    #pragma unroll
    for (int fj = 0; fj < 4; ++fj) {
        int j_abs = (wj << 6) + (fj << 4) + (lane & 15);
        bb[fj] = b1l[j_abs];
        wl[fj] = W2l[j_abs];
        wr[fj] = W2r[j_abs];
    }
    #pragma unroll
    for (int fm = 0; fm < 4; ++fm) {
        #pragma unroll
        for (int reg = 0; reg < 4; ++reg) {
            int rloc = (wm << 6) + (fm << 4) + ((lane >> 4) << 2) + reg;
            float tp = 0.f, rp = 0.f;
            #pragma unroll
            for (int fj = 0; fj < 4; ++fj) {
                float h = fmaxf(acc[fm][fj][reg] + bb[fj], 0.0f);
                tp += wl[fj] * h;
                rp += wr[fj] * h;
            }
            #pragma unroll
            for (int mask = 1; mask < 16; mask <<= 1) {
                tp += __shfl_xor(tp, mask, 64);
                rp += __shfl_xor(rp, mask, 64);
            }
            if ((lane & 15) == 0) {
                TpL[rloc][wj] = tp;
                RpL[rloc][wj] = rp;
            }
        }
    }
    __syncthreads();
    if (tid < 128) {
        int row = m0 + tid;
        if (row < Nn) {
            tv[row] = TpL[tid][0] + TpL[tid][1] + TpL[tid][2] + TpL[tid][3];
            rv[row] = RpL[tid][0] + RpL[tid][1] + RpL[tid][2] + RpL[tid][3];
        }
    }
}

__global__ void final_k(const float* __restrict__ t, const int* __restrict__ row_ptr,
                        const int* __restrict__ csr, const float* __restrict__ r,
                        const float* __restrict__ b2l,
                        const float* __restrict__ Wmu, const float* __restrict__ bmu,
                        const float* __restrict__ Wlv, const float* __restrict__ blv,
                        const float* __restrict__ eps, float* __restrict__ out, int Nn) {
    int i = blockIdx.x * blockDim.x + threadIdx.x;
    if (i >= Nn) return;
    int beg = row_ptr[i], end = row_ptr[i + 1];
    float s = 0.f;
    for (int j = beg; j < end; ++j) s += t[csr[j]];
    float z = s / fmaxf((float)(end - beg), 1.0f) + b2l[0] + r[i];
    float mu = z * Wmu[0] + bmu[0];
    float lv = z * Wlv[0] + blv[0];
    out[i] = mu + eps[i] * expf(lv);
}

extern "C" void kernel_launch(void* const* d_in, const int* in_sizes, int n_in,
                              void* d_out, int out_size, void* d_ws, size_t ws_size,
                              hipStream_t stream) {
    const float* x   = (const float*)d_in[0];
    const int*   ei  = (const int*)d_in[1];
    const float* W1l = (const float*)d_in[2];
    const float* b1l = (const float*)d_in[3];
    const float* W1r = (const float*)d_in[4];
    const float* W2l = (const float*)d_in[5];
    const float* b2l = (const float*)d_in[6];
    const float* W2r = (const float*)d_in[7];
    // d_in[8..10] = Wal, bal, War : dead (softmax over size-1 axis == 1)
    const float* Wmu = (const float*)d_in[11];
    const float* bmu = (const float*)d_in[12];
    const float* Wlv = (const float*)d_in[13];
    const float* blv = (const float*)d_in[14];
    const float* eps = (const float*)d_in[15];
    float* out = (float*)d_out;

    const int Nn = in_sizes[0] / F_DIM;   // 100000
    const int E  = in_sizes[1] / 2;       // 1600000
    const int* src = ei;
    const int* dst = ei + E;
    const int nbuk = (Nn + BUK_SZ - 1) >> BUK_BITS;      // 782
    const int chunk = (E + GROUPS - 1) / GROUPS;         // 12500

    char* ws = (char*)d_ws;
    float*          tv      = (float*)(ws + 0);               // N
    float*          rv      = (float*)(ws + 400000);          // N
    int*            row_ptr = (int*)(ws + 800000);            // N+1
    int*            bbase   = (int*)(ws + 1200064);           // nbuk+1
    int*            hist    = (int*)(ws + 1203264);           // GROUPS*nbuk
    int*            gbase   = (int*)(ws + 1603648);           // nbuk*GROUPS
    int*            csr     = (int*)(ws + 2004032);           // E ints
    // Z region: ebuf (E u32, dead after fill3) then aggb (N*128 bf16)
    unsigned*       ebuf    = (unsigned*)(ws + 8404032);
    unsigned short* aggb    = (unsigned short*)(ws + 8404032);
    unsigned short* xb      = (unsigned short*)(ws + 34004032);  // N*128 bf16
    unsigned short* Wb      = (unsigned short*)(ws + 59604032);  // 256*256 bf16

    int n4 = Nn * F_DIM / 4;
    cvt_prep<<<256 + (n4 + 255) / 256, 256, 0, stream>>>(x, xb, W1l, W1r, Wb, n4);

    hist_k<<<GROUPS, 256, 0, stream>>>(dst, hist, E, nbuk, chunk);
    sumscan_k<<<1, 1024, 0, stream>>>(hist, bbase, nbuk);
    colscan_k<<<nbuk, GROUPS, 0, stream>>>(hist, bbase, gbase, nbuk);
    scatter2_k<<<GROUPS, 256, 0, stream>>>(src, dst, gbase, ebuf, E, nbuk, chunk);
    fill3_k<<<nbuk, 256, 0, stream>>>(ebuf, bbase, row_ptr, csr, Nn, nbuk);

    gather_mean<<<(Nn + 7) / 8, 256, 0, stream>>>(xb, row_ptr, csr, aggb, Nn);

    gemm_big<<<(Nn + 127) / 128, 512, 0, stream>>>(aggb, xb, Wb, b1l,
                                                   W2l, W2r, tv, rv, Nn);

    final_k<<<(Nn + 255) / 256, 256, 0, stream>>>(tv, row_ptr, csr, rv, b2l,
                                                  Wmu, bmu, Wlv, blv, eps, out, Nn);
}